// Round 16
// baseline (394.450 us; speedup 1.0000x reference)
//
#include <hip/hip_runtime.h>
#include <hip/hip_bf16.h>
#include <math.h>

#define NN 512
#define HH 128
#define INDIM 64
#define BB 256
#define NE 4096               // directed edge count (2*E_UND)
#define MROWS (BB*NN)         // 131072
#define OUT0 (BB*NN*HH)       // 16777216 floats, start of C in d_out

typedef __attribute__((ext_vector_type(8))) short short8v;
typedef __attribute__((ext_vector_type(4))) float float4v;

__device__ __forceinline__ unsigned short f2bf(float f) {
  unsigned u = __float_as_uint(f);
  unsigned r = (u + 0x7fffu + ((u >> 16) & 1u)) >> 16;   // RNE
  return (unsigned short)r;
}
__device__ __forceinline__ float bf2f(unsigned short b) {
  return __uint_as_float(((unsigned)b) << 16);
}

// ---------------------------------------------------------------------------
// C = softmax(logits,-1) * adj * dir; C /= max(rowsum, 1e-8)
// ---------------------------------------------------------------------------
__global__ __launch_bounds__(256) void k_causalC(
    const float* __restrict__ logits, const float* __restrict__ adj,
    const float* __restrict__ dir, float* __restrict__ Cout)
{
  const int row = blockIdx.x;
  const int t = threadIdx.x;
  __shared__ float red[256];
  const float* lrow = logits + (size_t)row * NN;
  float v0 = lrow[t], v1 = lrow[t + 256];
  float mx = fmaxf(v0, v1);
  red[t] = mx; __syncthreads();
  for (int s = 128; s > 0; s >>= 1) { if (t < s) red[t] = fmaxf(red[t], red[t + s]); __syncthreads(); }
  mx = red[0]; __syncthreads();
  float e0 = __expf(v0 - mx), e1 = __expf(v1 - mx);
  red[t] = e0 + e1; __syncthreads();
  for (int s = 128; s > 0; s >>= 1) { if (t < s) red[t] += red[t + s]; __syncthreads(); }
  float sumE = red[0]; __syncthreads();
  float m0 = adj[(size_t)row * NN + t] * dir[(size_t)row * NN + t];
  float m1 = adj[(size_t)row * NN + t + 256] * dir[(size_t)row * NN + t + 256];
  float me0 = e0 * m0, me1 = e1 * m1;
  red[t] = me0 + me1; __syncthreads();
  for (int s = 128; s > 0; s >>= 1) { if (t < s) red[t] += red[t + s]; __syncthreads(); }
  float sumME = red[0];
  float sm = sumME / sumE;
  float denom = fmaxf(sm, 1e-8f) * sumE;
  Cout[(size_t)row * NN + t]       = me0 / denom;
  Cout[(size_t)row * NN + t + 256] = me1 / denom;
}

// ---------------------------------------------------------------------------
// CSR build for the GCN aggregation.
// ---------------------------------------------------------------------------
__global__ __launch_bounds__(512) void k_csr(const int* __restrict__ ei,
                                             int* __restrict__ rp,
                                             int* __restrict__ ci,
                                             float* __restrict__ cw)
{
  __shared__ int scnt[512];
  __shared__ float sdinv[512];
  __shared__ int sval[512];
  __shared__ int scur[512];
  const int t = threadIdx.x;
  const int* src = ei;
  const int* dst = ei + NE;
  scnt[t] = 0;
  __syncthreads();
  for (int e = t; e < NE; e += 512) atomicAdd(&scnt[dst[e]], 1);
  __syncthreads();
  const int deg = scnt[t] + 1;
  sdinv[t] = rsqrtf((float)deg);
  sval[t] = deg;
  __syncthreads();
  for (int off = 1; off < 512; off <<= 1) {
    int add = (t >= off) ? sval[t - off] : 0;
    __syncthreads();
    sval[t] += add;
    __syncthreads();
  }
  const int excl = sval[t] - deg;
  rp[t] = excl;
  if (t == 511) rp[512] = excl + deg;
  ci[excl] = t;
  cw[excl] = sdinv[t] * sdinv[t];
  scur[t] = excl + 1;
  __syncthreads();
  for (int e = t; e < NE; e += 512) {
    int s = src[e], d = dst[e];
    int p = atomicAdd(&scur[d], 1);
    ci[p] = s;
    cw[p] = sdinv[s] * sdinv[d];
  }
}

// ---------------------------------------------------------------------------
// CSR build for the causal-attention mask C (batch-independent, ~9 nnz/row).
// ---------------------------------------------------------------------------
__global__ __launch_bounds__(512) void k_ccsr(const int* __restrict__ ei,
                                              const float* __restrict__ Cmat,
                                              int* __restrict__ rp,
                                              int* __restrict__ ci,
                                              float* __restrict__ cw)
{
  __shared__ unsigned bm[512 * 16];      // 512 rows x 512-bit
  __shared__ int cnt[512];
  __shared__ int sval[512];
  __shared__ int cur[512];
  const int t = threadIdx.x;
  const int* src = ei;
  const int* dst = ei + NE;
  for (int i = t; i < 512 * 16; i += 512) bm[i] = 0u;
  __syncthreads();
  bm[t * 16 + (t >> 5)] |= (1u << (t & 31));
  cnt[t] = 1;
  __syncthreads();
  for (int e = t; e < NE; e += 512) {
    int r = src[e], c = dst[e];
    if (Cmat[(size_t)r * NN + c] > 0.f) {
      unsigned bit = 1u << (c & 31);
      unsigned old = atomicOr(&bm[r * 16 + (c >> 5)], bit);
      if (!(old & bit)) atomicAdd(&cnt[r], 1);
    }
  }
  __syncthreads();
  const int myc = cnt[t];
  sval[t] = myc;
  __syncthreads();
  for (int off = 1; off < 512; off <<= 1) {
    int add = (t >= off) ? sval[t - off] : 0;
    __syncthreads();
    sval[t] += add;
    __syncthreads();
  }
  const int excl = sval[t] - myc;
  rp[t] = excl;
  if (t == 511) rp[512] = excl + myc;
  ci[excl] = t;
  cw[excl] = Cmat[(size_t)t * NN + t];
  cur[t] = excl + 1;
  bm[t * 16 + (t >> 5)] &= ~(1u << (t & 31));
  __syncthreads();
  for (int e = t; e < NE; e += 512) {
    int r = src[e], c = dst[e];
    if (Cmat[(size_t)r * NN + c] > 0.f) {
      unsigned bit = 1u << (c & 31);
      unsigned old = atomicAnd(&bm[r * 16 + (c >> 5)], ~bit);
      if (old & bit) {
        int p = atomicAdd(&cur[r], 1);
        ci[p] = c;
        cw[p] = Cmat[(size_t)r * NN + c];
      }
    }
  }
}

// ---------------------------------------------------------------------------
// Sparse GCN aggregation body (R14: 2-deep pipeline, validated).
// ---------------------------------------------------------------------------
__device__ __forceinline__ void gcn_body(
    int bid, const unsigned short* __restrict__ hW,
    const int* __restrict__ rp, const int* __restrict__ ci,
    const float* __restrict__ cw, const float* __restrict__ bias,
    unsigned short* __restrict__ out, int OS, int OC0)
{
  const int i5 = bid >> 3;
  const int ng = i5 & 31;                // node-group varies fastest on XCD
  const int b = (bid & 7) * 32 + (i5 >> 5);
  const int t = threadIdx.x;
  const int node = ng * 16 + (t >> 4);
  const int f0 = (t & 15) * 8;

  float bcol[8];
  #pragma unroll
  for (int k = 0; k < 8; k++) bcol[k] = bias[f0 + k];

  const unsigned short* base = hW + (size_t)b * 512 * 128;
  const int beg = rp[node], end = rp[node + 1];
  float acc[8] = {0.f, 0.f, 0.f, 0.f, 0.f, 0.f, 0.f, 0.f};
  int j = beg;
  float w = cw[j];
  int m = ci[j];
  short8v v = *(const short8v*)&base[(size_t)m * 128 + f0];
  for (; j < end; ) {
    const int jn = (j + 1 < end) ? j + 1 : j;
    const float w2 = cw[jn];
    const int m2 = ci[jn];
    short8v v2 = *(const short8v*)&base[(size_t)m2 * 128 + f0];
    #pragma unroll
    for (int k = 0; k < 8; k++) acc[k] += w * bf2f((unsigned short)v[k]);
    j++;
    w = w2; v = v2;
  }
  short8v o;
  #pragma unroll
  for (int k = 0; k < 8; k++) {
    float vv = fmaxf(acc[k] + bcol[k], 0.f);
    o[k] = (short)f2bf(vv);
  }
  *(short8v*)&out[((size_t)(b * 512 + node)) * OS + OC0 + f0] = o;
}

__global__ __launch_bounds__(256) void k_gcn(
    const unsigned short* __restrict__ hW,
    const int* __restrict__ rp, const int* __restrict__ ci,
    const float* __restrict__ cw, const float* __restrict__ bias,
    unsigned short* __restrict__ out, int OS, int OC0)
{
  gcn_body(blockIdx.x, hW, rp, ci, cw, bias, out, OS, OC0);
}

// ---------------------------------------------------------------------------
// Sparse masked attention body with EXPLICIT local thread id lt (R16: lets
// a 512-thread block run two virtual 256-thread attn blocks).  Identical
// arithmetic to the R8-validated 2-deep-pipeline body.
// ---------------------------------------------------------------------------
__device__ __forceinline__ void sattn_body_t(
    int bid, int lt, const unsigned short* __restrict__ Qbf,
    const unsigned short* __restrict__ Kbf, const unsigned short* __restrict__ Vbf,
    const int* __restrict__ rp, const int* __restrict__ ci,
    const float* __restrict__ cw, unsigned short* __restrict__ Ocb)
{
  const int i5 = bid >> 3;
  const int ng = i5 & 31;
  const int b = (bid & 7) * 32 + (i5 >> 5);
  const int node = ng * 16 + (lt >> 4);
  const int f0 = (lt & 15) * 8;
  const float scale = 0.088388347648318447f;   // 1/sqrt(128)

  const size_t rowq = ((size_t)(b * 512 + node)) * 128 + f0;
  short8v qv = *(const short8v*)&Qbf[rowq];
  float qf[8];
  #pragma unroll
  for (int k = 0; k < 8; k++) qf[k] = bf2f((unsigned short)qv[k]);

  const unsigned short* Kb = Kbf + (size_t)b * 512 * 128;
  const unsigned short* Vb = Vbf + (size_t)b * 512 * 128;
  const int beg = rp[node], end = rp[node + 1];
  float acc[8] = {0.f, 0.f, 0.f, 0.f, 0.f, 0.f, 0.f, 0.f};
  float sw = 0.f;
  int j = beg;
  float w0 = cw[j];
  int m = ci[j];
  short8v kv = *(const short8v*)&Kb[(size_t)m * 128 + f0];
  short8v vv = *(const short8v*)&Vb[(size_t)m * 128 + f0];
  for (; j < end; ) {
    const int jn = (j + 1 < end) ? j + 1 : j;
    const float w02 = cw[jn];
    const int m2 = ci[jn];
    short8v kv2 = *(const short8v*)&Kb[(size_t)m2 * 128 + f0];
    short8v vv2 = *(const short8v*)&Vb[(size_t)m2 * 128 + f0];
    float part = 0.f;
    #pragma unroll
    for (int k = 0; k < 8; k++) part += qf[k] * bf2f((unsigned short)kv[k]);
    part += __shfl_xor(part, 1);
    part += __shfl_xor(part, 2);
    part += __shfl_xor(part, 4);
    part += __shfl_xor(part, 8);       // all 16 lanes of the node hold S
    float w = __expf(part * scale) * w0;
    sw += w;
    #pragma unroll
    for (int k = 0; k < 8; k++) acc[k] += w * bf2f((unsigned short)vv[k]);
    j++;
    w0 = w02; kv = kv2; vv = vv2;
  }
  float inv = 1.0f / sw;
  short8v o;
  #pragma unroll
  for (int k = 0; k < 8; k++) o[k] = (short)f2bf(acc[k] * inv);
  *(short8v*)&Ocb[((size_t)(b * 512 + node)) * 256 + f0] = o;
}

// ---------------------------------------------------------------------------
// Weight transpose+convert (R7-proven LDS tile transpose, 56 blocks).
// ---------------------------------------------------------------------------
__global__ __launch_bounds__(256) void k_wt(
    const float* s0, const float* s1, const float* s2, const float* s3,
    const float* s4, const float* s5, const float* s6,
    unsigned short* d0, unsigned short* d1, unsigned short* d2, unsigned short* d3,
    unsigned short* d4, unsigned short* d5, unsigned short* d6)
{
  const float* srcs[7] = {s0, s1, s2, s3, s4, s5, s6};
  unsigned short* dsts[7] = {d0, d1, d2, d3, d4, d5, d6};
  const int Ks[7] = {64, 128, 128, 128, 128, 128, 256};
  const int j = blockIdx.x >> 3;
  const int nc = blockIdx.x & 7;
  const float* s = srcs[j];
  unsigned short* d = dsts[j];
  const int K = Ks[j];
  const int STRW = K + 8;
  const int n0 = nc * 16;
  __shared__ short tile[16 * 264];       // max stride 256+8
  const int t = threadIdx.x;
  for (int i = t; i < K * 16; i += 256) {
    int k = i >> 4, nn = i & 15;
    tile[nn * STRW + k] = (short)f2bf(s[k * 128 + n0 + nn]);
  }
  __syncthreads();
  for (int i = t; i < K * 2; i += 256) {   // K*16/8 vector stores
    int nn = (i * 8) / K;
    int k  = (i * 8) % K;
    *(short8v*)&d[(size_t)(n0 + nn) * K + k] =
        *(const short8v*)&tile[nn * STRW + k];
  }
}

// ---------------------------------------------------------------------------
// R16: merged wave-independent GEMM (g1@W1 -> A0) || sparse attention.
// The two are INDEPENDENT (GEMM reads B0 from gcn-L0; attn reads Q/K/V
// from hqkv4) and stress DIFFERENT pipes (MFMA/stream vs latency/VALU) —
// the heterogeneous merge R10's same-bottleneck merge couldn't be.
// Blocks [0,GWB): 512t GEMM body (R13-proven).  Blocks [GWB,GWB+4096):
// two virtual 256t attn blocks each (vbid = (bid-GWB)*2 + (t>>8)).
// ---------------------------------------------------------------------------
#define GWB 512
__global__ __launch_bounds__(512) void k_wa(
    const unsigned short* __restrict__ Abf,    // B0 (g1)
    const unsigned short* __restrict__ Wt,     // G1t
    unsigned short* __restrict__ Gout,         // A0
    const unsigned short* __restrict__ Qbf, const unsigned short* __restrict__ Kbf,
    const unsigned short* __restrict__ Vbf,
    const int* __restrict__ arp, const int* __restrict__ aci,
    const float* __restrict__ acw,
    unsigned short* __restrict__ Ocb)          // D0 col0 (stride 256)
{
  constexpr int STR = 136;                  // 128 + 8 pad
  __shared__ short Ws[128 * STR];           // 34816 B
  __shared__ short rep[8 * 2048];           // 32768 B, 4KB per wave
  const int t = threadIdx.x;

  if (blockIdx.x >= GWB) {
    const int vbid = (blockIdx.x - GWB) * 2 + (t >> 8);
    sattn_body_t(vbid, t & 255, Qbf, Kbf, Vbf, arp, aci, acw, Ocb);
    return;
  }

  const int wave = t >> 6, lane = t & 63;
  const int l15 = lane & 15, quad = lane >> 4;
  short* rw = rep + wave * 2048;

  for (int i = t; i < 128 * 16; i += 512) {
    int n = i >> 4, seg = i & 15;
    *(short8v*)&Ws[n * STR + seg * 8] =
        *(const short8v*)&Wt[(size_t)n * 128 + seg * 8];
  }
  __syncthreads();                          // Ws visible — the ONLY barrier

  const int nwaves = GWB * 8;
  int tile = blockIdx.x * 8 + wave;
  short8v af[4], afn[4];
  if (tile < MROWS / 16) {
    #pragma unroll
    for (int dc = 0; dc < 4; dc++)
      af[dc] = *(const short8v*)&Abf[((size_t)(tile * 16 + l15)) * 128 + dc * 32 + quad * 8];
  }
  while (tile < MROWS / 16) {
    const int ntile = tile + nwaves;
    if (ntile < MROWS / 16) {
      #pragma unroll
      for (int dc = 0; dc < 4; dc++)
        afn[dc] = *(const short8v*)&Abf[((size_t)(ntile * 16 + l15)) * 128 + dc * 32 + quad * 8];
    }
    float4v acc[8];
    #pragma unroll
    for (int nt = 0; nt < 8; nt++) acc[nt] = (float4v){0.f, 0.f, 0.f, 0.f};
    #pragma unroll
    for (int k32 = 0; k32 < 4; k32++) {
      #pragma unroll
      for (int nt = 0; nt < 8; nt++) {
        short8v wf = *(const short8v*)&Ws[(nt * 16 + l15) * STR + k32 * 32 + quad * 8];
        acc[nt] = __builtin_amdgcn_mfma_f32_16x16x32_bf16(af[k32], wf, acc[nt], 0, 0, 0);
      }
    }
    #pragma unroll
    for (int nt = 0; nt < 8; nt++)
      #pragma unroll
      for (int r = 0; r < 4; r++) {
        float v = acc[nt][r];
        rw[(quad * 4 + r) * 128 + nt * 16 + l15] = (short)f2bf(v);
      }
    asm volatile("s_waitcnt lgkmcnt(0)" ::: "memory");
    __builtin_amdgcn_sched_barrier(0);
    #pragma unroll
    for (int p = 0; p < 4; p++) {
      int row16 = (lane >> 4) + p * 4, seg = lane & 15;
      short8v vv = *(const short8v*)&rw[row16 * 128 + seg * 8];
      *(short8v*)&Gout[((size_t)(tile * 16 + row16)) * 128 + seg * 8] = vv;
    }
    tile = ntile;
    #pragma unroll
    for (int dc = 0; dc < 4; dc++) af[dc] = afn[dc];
  }
}

// ---------------------------------------------------------------------------
// bf16 MFMA GEMM (R7-proven).  Used ONLY for the final fused-LN GEMM
// (KD=256, OMODE2).  LDS repack keeps fp32 stores full-line (R14 lesson).
// ---------------------------------------------------------------------------
#define GNT 4
template<int KD, bool RELU, bool BATCHW, int OMODE, bool AF32>
__global__ __launch_bounds__(256) void k_bgemm(
    const void* __restrict__ Ap, const unsigned short* __restrict__ Wt,
    const float* __restrict__ bias, void* __restrict__ Out, int OS,
    const float* __restrict__ lng, const float* __restrict__ lnb)
{
  constexpr int KCH = (KD < 128) ? KD : 128;
  constexpr int STR = KCH + 8;
  constexpr bool WONCE = (KD <= 128);
  constexpr int ASH = (64 * STR > 8192) ? 64 * STR : 8192;   // shorts
  constexpr int TRIPS = KCH / 32;        // staging iterations per thread
  __shared__ short lds[ASH + 128 * STR];
  short* As = lds;
  short* Ws = lds + ASH;
  const unsigned short* Abf = (const unsigned short*)Ap;
  const float* Af = (const float*)Ap;
  const int t = threadIdx.x;
  const int wave = t >> 6, lane = t & 63;
  const int l15 = lane & 15, quad = lane >> 4;

  short8v ap[TRIPS];
  float4 fa[TRIPS], fb[TRIPS];

  auto LOADC = [&](int rb, int kc) {
    #pragma unroll
    for (int j = 0; j < TRIPS; j++) {
      int i = t + j * 256;
      int r = i / (KCH / 8), seg = i % (KCH / 8);
      if (AF32) {
        const float* sp = &Af[(size_t)(rb + r) * KD + kc + seg * 8];
        fa[j] = *(const float4*)sp;
        fb[j] = *(const float4*)(sp + 4);
      } else {
        int arow = BATCHW ? ((rb & 511) + r) : (rb + r);
        ap[j] = *(const short8v*)&Abf[(size_t)arow * KD + kc + seg * 8];
      }
    }
  };
  auto STOREC = [&]() {
    #pragma unroll
    for (int j = 0; j < TRIPS; j++) {
      int i = t + j * 256;
      int r = i / (KCH / 8), seg = i % (KCH / 8);
      if (AF32) {
        short8v pk;
        pk[0] = (short)f2bf(fa[j].x); pk[1] = (short)f2bf(fa[j].y);
        pk[2] = (short)f2bf(fa[j].z); pk[3] = (short)f2bf(fa[j].w);
        pk[4] = (short)f2bf(fb[j].x); pk[5] = (short)f2bf(fb[j].y);
        pk[6] = (short)f2bf(fb[j].z); pk[7] = (short)f2bf(fb[j].w);
        *(short8v*)&As[r * STR + seg * 8] = pk;
      } else {
        *(short8v*)&As[r * STR + seg * 8] = ap[j];
      }
    }
  };

  float bcol[8];
  #pragma unroll
  for (int nt = 0; nt < 8; nt++) bcol[nt] = bias ? bias[nt * 16 + l15] : 0.f;
  float gcol[8], bbcol[8];
  if (OMODE == 2) {
    #pragma unroll
    for (int nt = 0; nt < 8; nt++) { gcol[nt] = lng[nt * 16 + l15]; bbcol[nt] = lnb[nt * 16 + l15]; }
  }

  for (int g = blockIdx.x; g < (MROWS / 64) / GNT; g += gridDim.x) {
    if (WONCE) {
      const int b0 = (g * GNT * 64) >> 9;
      const unsigned short* Wb = BATCHW ? (Wt + (size_t)b0 * 128 * KD) : Wt;
      for (int i = t; i < 128 * (KCH / 8); i += 256) {
        int n = i / (KCH / 8), seg = i % (KCH / 8);
        *(short8v*)&Ws[n * STR + seg * 8] =
            *(const short8v*)&Wb[(size_t)n * KD + seg * 8];
      }
    }
    LOADC(g * GNT * 64, 0);                // prologue prefetch: tile 0 chunk 0
    for (int tt = 0; tt < GNT; tt++) {
      const int tile = g * GNT + tt;
      const int rowbase = tile * 64;
      const int b = rowbase >> 9;
      float4v acc[8];
      #pragma unroll
      for (int nt = 0; nt < 8; nt++) acc[nt] = (float4v){0.f, 0.f, 0.f, 0.f};

      for (int kc = 0; kc < KD; kc += KCH) {
        __syncthreads();                   // protect prior reads of As/Ws/rep
        STOREC();                          // prefetched regs -> LDS
        if (!WONCE) {
          const unsigned short* Wb = BATCHW ? (Wt + (size_t)b * 128 * KD) : Wt;
          for (int i = t; i < 128 * (KCH / 8); i += 256) {
            int n = i / (KCH / 8), seg = i % (KCH / 8);
            *(short8v*)&Ws[n * STR + seg * 8] =
                *(const short8v*)&Wb[(size_t)n * KD + kc + seg * 8];
          }
        }
        __syncthreads();
        {
          int nkc = kc + KCH, ntt = tt;
          if (nkc >= KD) { nkc = 0; ntt = tt + 1; }
          if (ntt < GNT) LOADC((g * GNT + ntt) * 64, nkc);
        }
        #pragma unroll
        for (int k32 = 0; k32 < KCH / 32; k32++) {
          short8v af = *(const short8v*)&As[(wave * 16 + l15) * STR + k32 * 32 + quad * 8];
          #pragma unroll
          for (int nt = 0; nt < 8; nt++) {
            short8v wf = *(const short8v*)&Ws[(nt * 16 + l15) * STR + k32 * 32 + quad * 8];
            acc[nt] = __builtin_amdgcn_mfma_f32_16x16x32_bf16(af, wf, acc[nt], 0, 0, 0);
          }
        }
      }

      __syncthreads();                         // all waves done reading As/Ws
      if (OMODE == 0) {
        short* rep = As + wave * 2048;
        #pragma unroll
        for (int nt = 0; nt < 8; nt++)
          #pragma unroll
          for (int r = 0; r < 4; r++) {
            float v = acc[nt][r] + bcol[nt];
            if (RELU) v = fmaxf(v, 0.f);
            rep[(quad * 4 + r) * 128 + nt * 16 + l15] = (short)f2bf(v);
          }
        __syncthreads();
        unsigned short* Ob = (unsigned short*)Out;
        #pragma unroll
        for (int p = 0; p < 4; p++) {
          int row16 = (lane >> 4) + p * 4, seg = lane & 15;
          short8v vv = *(const short8v*)&rep[row16 * 128 + seg * 8];
          *(short8v*)&Ob[(size_t)(rowbase + wave * 16 + row16) * OS + seg * 8] = vv;
        }
      } else if (OMODE == 1) {
        short* rep = As + wave * 2048;         // [c:128][node:16]
        #pragma unroll
        for (int nt = 0; nt < 8; nt++)
          #pragma unroll
          for (int r = 0; r < 4; r++) {
            float v = acc[nt][r] + bcol[nt];
            if (RELU) v = fmaxf(v, 0.f);
            rep[(nt * 16 + l15) * 16 + quad * 4 + r] = (short)f2bf(v);
          }
        __syncthreads();
        unsigned short* Ob = (unsigned short*)Out;
        int node0 = (rowbase & 511) + wave * 16;
        #pragma unroll
        for (int p = 0; p < 4; p++) {
          int idx = p * 64 + lane, c = idx >> 1, half = idx & 1;
          short8v vv = *(const short8v*)&rep[c * 16 + half * 8];
          *(short8v*)&Ob[((size_t)(b * 128 + c)) * 512 + node0 + half * 8] = vv;
        }
      } else {
        float* repw = (float*)lds + wave * 2048;   // Ws chunk data dead here
        float vv[8][4];
        float s[4] = {0, 0, 0, 0}, ss[4] = {0, 0, 0, 0};
        #pragma unroll
        for (int nt = 0; nt < 8; nt++)
          #pragma unroll
          for (int r = 0; r < 4; r++) {
            float v = acc[nt][r] + bcol[nt];
            vv[nt][r] = v;
            s[r] += v; ss[r] += v * v;
          }
        #pragma unroll
        for (int r = 0; r < 4; r++) {
          s[r] += __shfl_xor(s[r], 1);  s[r] += __shfl_xor(s[r], 2);
          s[r] += __shfl_xor(s[r], 4);  s[r] += __shfl_xor(s[r], 8);
          ss[r] += __shfl_xor(ss[r], 1); ss[r] += __shfl_xor(ss[r], 2);
          ss[r] += __shfl_xor(ss[r], 4); ss[r] += __shfl_xor(ss[r], 8);
        }
        #pragma unroll
        for (int r = 0; r < 4; r++) {
          float mu = s[r] * (1.0f / 128.0f);
          float var = ss[r] * (1.0f / 128.0f) - mu * mu;
          float inv = rsqrtf(var + 1e-5f);
          #pragma unroll
          for (int nt = 0; nt < 8; nt++)
            repw[(quad * 4 + r) * 128 + nt * 16 + l15] =
                (vv[nt][r] - mu) * inv * gcol[nt] + bbcol[nt];
        }
        __syncthreads();
        float* Of = (float*)Out;
        #pragma unroll
        for (int p = 0; p < 8; p++) {
          int row16 = (lane >> 5) + p * 2, seg = lane & 31;
          float4 o = *(const float4*)&repw[row16 * 128 + seg * 4];
          *(float4*)&Of[(size_t)(rowbase + wave * 16 + row16) * 128 + seg * 4] = o;
        }
      }
    }
  }
}

// ---------------------------------------------------------------------------
// R13: fused h + 4-way GEMM, 512-thread blocks (8 waves share one Ws).
// ---------------------------------------------------------------------------
__global__ __launch_bounds__(512) void k_hqkv4(
    const float* __restrict__ x,
    const unsigned short* __restrict__ Wint,   // 128 x 64 bf16 (n*64+k)
    const float* __restrict__ bin,
    const unsigned short* __restrict__ W0, const unsigned short* __restrict__ W1,
    const unsigned short* __restrict__ W2, const unsigned short* __restrict__ W3,
    const float* __restrict__ b1, const float* __restrict__ b2,
    const float* __restrict__ b3,
    unsigned short* __restrict__ O0, unsigned short* __restrict__ O1,
    unsigned short* __restrict__ O2, unsigned short* __restrict__ O3)
{
  constexpr int STR = 136;                  // Ws stride (128 + 8)
  constexpr int RSTR = 136;                 // rep stride
  __shared__ short Ws[128 * STR];           // 34816 B
  __shared__ short rep[8 * 2304];           // 36864 B
  const int t = threadIdx.x;
  const int wave = t >> 6, lane = t & 63;
  const int l15 = lane & 15, quad = lane >> 4;
  short* rw = rep + wave * 2304;

  const unsigned short* Wsrc[4] = {W0, W1, W2, W3};
  const float* Bsrc[4] = {nullptr, b1, b2, b3};
  unsigned short* Osrc[4] = {O0, O1, O2, O3};

  float bh[8];
  #pragma unroll
  for (int nt = 0; nt < 8; nt++) bh[nt] = bin[nt * 16 + l15];

  for (int g = blockIdx.x; g < MROWS / 256; g += gridDim.x) {
    // ---- phase 0: stage W_int (128x64) into Ws
    __syncthreads();                      // protect prior Ws reads (loop)
    for (int i = t; i < 128 * 8; i += 512) {
      int n = i >> 3, seg = i & 7;
      *(short8v*)&Ws[n * STR + seg * 8] =
          *(const short8v*)&Wint[(size_t)n * 64 + seg * 8];
    }
    __syncthreads();                      // Wint visible

    // ---- phase 1: h fragments for the 2 x 128-row tiles (wave-private)
    short8v af_all[2][4];
    #pragma unroll
    for (int tt = 0; tt < 2; tt++) {
      const int row0 = (g * 2 + tt) * 128 + wave * 16;   // this wave's 16 rows
      const float* xp = &x[(size_t)(row0 + l15) * 64 + quad * 16];
      float4 fx0 = *(const float4*)(xp);
      float4 fx1 = *(const float4*)(xp + 4);
      float4 fx2 = *(const float4*)(xp + 8);
      float4 fx3 = *(const float4*)(xp + 12);
      short8v px0, px1;
      px0[0] = (short)f2bf(fx0.x); px0[1] = (short)f2bf(fx0.y);
      px0[2] = (short)f2bf(fx0.z); px0[3] = (short)f2bf(fx0.w);
      px0[4] = (short)f2bf(fx1.x); px0[5] = (short)f2bf(fx1.y);
      px0[6] = (short)f2bf(fx1.z); px0[7] = (short)f2bf(fx1.w);
      px1[0] = (short)f2bf(fx2.x); px1[1] = (short)f2bf(fx2.y);
      px1[2] = (short)f2bf(fx2.z); px1[3] = (short)f2bf(fx2.w);
      px1[4] = (short)f2bf(fx3.x); px1[5] = (short)f2bf(fx3.y);
      px1[6] = (short)f2bf(fx3.z); px1[7] = (short)f2bf(fx3.w);
      *(short8v*)&rw[l15 * 72 + quad * 16]     = px0;   // x tile: 16 x 72
      *(short8v*)&rw[l15 * 72 + quad * 16 + 8] = px1;
      asm volatile("s_waitcnt lgkmcnt(0)" ::: "memory");
      __builtin_amdgcn_sched_barrier(0);

      float4v hacc[8];
      #pragma unroll
      for (int nt = 0; nt < 8; nt++) hacc[nt] = (float4v){0.f, 0.f, 0.f, 0.f};
      #pragma unroll
      for (int k32 = 0; k32 < 2; k32++) {
        short8v ax = *(const short8v*)&rw[l15 * 72 + k32 * 32 + quad * 8];
        #pragma unroll
        for (int nt = 0; nt < 8; nt++) {
          short8v wf = *(const short8v*)&Ws[(nt * 16 + l15) * STR + k32 * 32 + quad * 8];
          hacc[nt] = __builtin_amdgcn_mfma_f32_16x16x32_bf16(ax, wf, hacc[nt], 0, 0, 0);
        }
      }
      #pragma unroll
      for (int nt = 0; nt < 8; nt++)
        #pragma unroll
        for (int r = 0; r < 4; r++) {
          float v = fmaxf(hacc[nt][r] + bh[nt], 0.f);
          rw[(quad * 4 + r) * RSTR + nt * 16 + l15] = (short)f2bf(v);
        }
      asm volatile("s_waitcnt lgkmcnt(0)" ::: "memory");
      __builtin_amdgcn_sched_barrier(0);
      #pragma unroll
      for (int dc = 0; dc < 4; dc++)
        af_all[tt][dc] = *(const short8v*)&rw[l15 * RSTR + dc * 32 + quad * 8];
    }

    // ---- phase 2: four weight sets, MFMA from register A-fragments
    #pragma unroll
    for (int s = 0; s < 4; s++) {
      __syncthreads();                 // protect Ws reads (phase 1 / prior s)
      for (int i = t; i < 128 * 16; i += 512) {
        int n = i >> 4, seg = i & 15;
        *(short8v*)&Ws[n * STR + seg * 8] =
            *(const short8v*)&Wsrc[s][(size_t)n * 128 + seg * 8];
      }
      float bcol[8];
      #pragma unroll
      for (int nt = 0; nt < 8; nt++) bcol[nt] = Bsrc[s] ? Bsrc[s][nt * 16 + l15] : 0.f;
      __syncthreads();                 // Ws visible

      #pragma unroll
      for (int tt = 0; tt < 2; tt++) {
        const int rowbase = (g * 2 + tt) * 128;
        float4v acc[8];
        #pragma unroll
        for (int nt = 0; nt < 8; nt++) acc[nt] = (float4v){0.f, 0.f, 0.f, 0.f};
        #pragma unroll
        for (int k32 = 0; k32 < 4; k32++) {
          #pragma unroll
          for (int nt = 0; nt < 8; nt++) {
            short8v wf = *(const short8v*)&Ws[(nt * 16 + l15) * STR + k32 * 32 + quad * 8];
            acc[nt] = __builtin_amdgcn_mfma_f32_16x16x32_bf16(af_all[tt][k32], wf, acc[nt], 0, 0, 0);
          }
        }
        #pragma unroll
        for (int nt = 0; nt < 8; nt++)
          #pragma unroll
          for (int r = 0; r < 4; r++) {
            float v = acc[nt][r] + bcol[nt];
            rw[(quad * 4 + r) * RSTR + nt * 16 + l15] = (short)f2bf(v);
          }
        asm volatile("s_waitcnt lgkmcnt(0)" ::: "memory");
        __builtin_amdgcn_sched_barrier(0);
        unsigned short* Ob = Osrc[s];
        #pragma unroll
        for (int p = 0; p < 4; p++) {
          int row16 = (lane >> 4) + p * 4, seg = lane & 15;
          short8v vv = *(const short8v*)&rw[row16 * RSTR + seg * 8];
          *(short8v*)&Ob[(size_t)(rowbase + wave * 16 + row16) * 128 + seg * 8] = vv;
        }
      }
    }
  }
}

// ---------------------------------------------------------------------------
// ws layout: 5 x 33.5MB slots (A0,B0,C0,D0[2]) + AUX.
// V bf16 overlays d_out first half; K bf16 (E0) overlays d_out second half.
// ---------------------------------------------------------------------------
extern "C" void kernel_launch(void* const* d_in, const int* in_sizes, int n_in,
                              void* d_out, int out_size, void* d_ws, size_t ws_size,
                              hipStream_t stream)
{
  const float* x     = (const float*)d_in[0];
  const int*   ei    = (const int*)d_in[1];
  const float* adj   = (const float*)d_in[2];
  const float* dmask = (const float*)d_in[3];
  const float* clog  = (const float*)d_in[4];
  const float* W_in  = (const float*)d_in[5];
  const float* b_in  = (const float*)d_in[6];
  const float* Wq    = (const float*)d_in[7];
  const float* bq    = (const float*)d_in[8];
  const float* Wk    = (const float*)d_in[9];
  const float* bk    = (const float*)d_in[10];
  const float* Wv    = (const float*)d_in[11];
  const float* bv    = (const float*)d_in[12];
  const float* gcnW  = (const float*)d_in[13];
  const float* gcnB  = (const float*)d_in[14];
  const float* Wf    = (const float*)d_in[15];
  const float* bf    = (const float*)d_in[16];
  const float* lng   = (const float*)d_in[17];
  const float* lnb   = (const float*)d_in[18];

  float* outp = (float*)d_out;
  float* Cmat = outp + OUT0;

  char* W = (char*)d_ws;
  const size_t SLOT = (size_t)MROWS * 128 * 2;       // 33,554,432 B
  unsigned short* A0 = (unsigned short*)(W);
  unsigned short* B0 = (unsigned short*)(W + SLOT);
  unsigned short* C0 = (unsigned short*)(W + 2 * SLOT);
  unsigned short* D0 = (unsigned short*)(W + 3 * SLOT);   // 2*SLOT bytes
  char* AUX = W + 5 * SLOT;
  int*   csr_rp = (int*)AUX;                              // 513 ints
  int*   csr_ci = csr_rp + 640;                           // 4608 ints
  float* csr_cw = (float*)(csr_ci + 4608);                // 4608 floats
  int*   crp    = (int*)(AUX + 131072);                   // C-CSR @128KB
  int*   cci    = crp + 640;                              // up to 8192
  float* ccw    = (float*)(cci + 8192);
  unsigned short* WB    = (unsigned short*)(AUX + 512 * 512 * 4) + 512 * 512 * 2;
  unsigned short* W_int = WB;            // 128x64
  unsigned short* Wqt   = WB + 8192;     // 128x128
  unsigned short* Wkt   = Wqt + 16384;
  unsigned short* Wvt   = Wkt + 16384;
  unsigned short* G0t   = Wvt + 16384;
  unsigned short* G1t   = G0t + 16384;
  unsigned short* Wft   = G1t + 16384;   // 128x256

  unsigned short* Vbf = (unsigned short*)outp;       // d_out half 1 (scratch)
  unsigned short* E0  = Vbf + (size_t)MROWS * 128;   // d_out half 2 (scratch)

  // --- prep ---
  k_causalC<<<512, 256, 0, stream>>>(clog, adj, dmask, Cmat);
  k_csr<<<1, 512, 0, stream>>>(ei, csr_rp, csr_ci, csr_cw);
  k_ccsr<<<1, 512, 0, stream>>>(ei, Cmat, crp, cci, ccw);
  k_wt<<<56, 256, 0, stream>>>(W_in, Wq, Wk, Wv, gcnW, gcnW + HH * HH, Wf,
                               W_int, Wqt, Wkt, Wvt, G0t, G1t, Wft);

  // --- fused h + 4-way GEMM: hW0 -> A0, Q -> C0, K -> E0, V -> Vbf ---
  k_hqkv4<<<512, 512, 0, stream>>>(
      x, W_int, b_in, G0t, Wqt, Wkt, Wvt, bq, bk, bv, A0, C0, E0, Vbf);
  // --- GCN layer 0 aggregation: g1 = relu(gather(A0) + b0) -> B0 ---
  k_gcn<<<8192, 256, 0, stream>>>(A0, csr_rp, csr_ci, csr_cw, gcnB, B0, 128, 0);
  // --- R16 merged: g1@W1 -> A0 (GEMM)  ||  attention -> D0 col0 ---
  k_wa<<<GWB + 4096, 512, 0, stream>>>(
      B0, G1t, A0, C0, E0, Vbf, crp, cci, ccw, D0);
  // --- GCN layer 1 aggregation: gather(A0) -> D0 col128 (stride 256) ---
  k_gcn<<<8192, 256, 0, stream>>>(A0, csr_rp, csr_ci, csr_cw, gcnB + HH, D0, 256, 128);
  // --- fuse + fused LayerNorm -> outp (proven k_bgemm OMODE2) ---
  k_bgemm<256, false, false, 2, false><<<512, 256, 0, stream>>>(
      D0, Wft, bf, outp, 128, lng, lnb);
}

// Round 17
// 356.897 us; speedup vs baseline: 1.1052x; 1.1052x over previous
//
#include <hip/hip_runtime.h>
#include <hip/hip_bf16.h>
#include <math.h>

#define NN 512
#define HH 128
#define INDIM 64
#define BB 256
#define NE 4096               // directed edge count (2*E_UND)
#define MROWS (BB*NN)         // 131072
#define OUT0 (BB*NN*HH)       // 16777216 floats, start of C in d_out

typedef __attribute__((ext_vector_type(8))) short short8v;
typedef __attribute__((ext_vector_type(4))) float float4v;

__device__ __forceinline__ unsigned short f2bf(float f) {
  unsigned u = __float_as_uint(f);
  unsigned r = (u + 0x7fffu + ((u >> 16) & 1u)) >> 16;   // RNE
  return (unsigned short)r;
}
__device__ __forceinline__ float bf2f(unsigned short b) {
  return __uint_as_float(((unsigned)b) << 16);
}

// ---------------------------------------------------------------------------
// C = softmax(logits,-1) * adj * dir; C /= max(rowsum, 1e-8)
// ---------------------------------------------------------------------------
__global__ __launch_bounds__(256) void k_causalC(
    const float* __restrict__ logits, const float* __restrict__ adj,
    const float* __restrict__ dir, float* __restrict__ Cout)
{
  const int row = blockIdx.x;
  const int t = threadIdx.x;
  __shared__ float red[256];
  const float* lrow = logits + (size_t)row * NN;
  float v0 = lrow[t], v1 = lrow[t + 256];
  float mx = fmaxf(v0, v1);
  red[t] = mx; __syncthreads();
  for (int s = 128; s > 0; s >>= 1) { if (t < s) red[t] = fmaxf(red[t], red[t + s]); __syncthreads(); }
  mx = red[0]; __syncthreads();
  float e0 = __expf(v0 - mx), e1 = __expf(v1 - mx);
  red[t] = e0 + e1; __syncthreads();
  for (int s = 128; s > 0; s >>= 1) { if (t < s) red[t] += red[t + s]; __syncthreads(); }
  float sumE = red[0]; __syncthreads();
  float m0 = adj[(size_t)row * NN + t] * dir[(size_t)row * NN + t];
  float m1 = adj[(size_t)row * NN + t + 256] * dir[(size_t)row * NN + t + 256];
  float me0 = e0 * m0, me1 = e1 * m1;
  red[t] = me0 + me1; __syncthreads();
  for (int s = 128; s > 0; s >>= 1) { if (t < s) red[t] += red[t + s]; __syncthreads(); }
  float sumME = red[0];
  float sm = sumME / sumE;
  float denom = fmaxf(sm, 1e-8f) * sumE;
  Cout[(size_t)row * NN + t]       = me0 / denom;
  Cout[(size_t)row * NN + t + 256] = me1 / denom;
}

// ---------------------------------------------------------------------------
// CSR build for the GCN aggregation.
// ---------------------------------------------------------------------------
__global__ __launch_bounds__(512) void k_csr(const int* __restrict__ ei,
                                             int* __restrict__ rp,
                                             int* __restrict__ ci,
                                             float* __restrict__ cw)
{
  __shared__ int scnt[512];
  __shared__ float sdinv[512];
  __shared__ int sval[512];
  __shared__ int scur[512];
  const int t = threadIdx.x;
  const int* src = ei;
  const int* dst = ei + NE;
  scnt[t] = 0;
  __syncthreads();
  for (int e = t; e < NE; e += 512) atomicAdd(&scnt[dst[e]], 1);
  __syncthreads();
  const int deg = scnt[t] + 1;
  sdinv[t] = rsqrtf((float)deg);
  sval[t] = deg;
  __syncthreads();
  for (int off = 1; off < 512; off <<= 1) {
    int add = (t >= off) ? sval[t - off] : 0;
    __syncthreads();
    sval[t] += add;
    __syncthreads();
  }
  const int excl = sval[t] - deg;
  rp[t] = excl;
  if (t == 511) rp[512] = excl + deg;
  ci[excl] = t;
  cw[excl] = sdinv[t] * sdinv[t];
  scur[t] = excl + 1;
  __syncthreads();
  for (int e = t; e < NE; e += 512) {
    int s = src[e], d = dst[e];
    int p = atomicAdd(&scur[d], 1);
    ci[p] = s;
    cw[p] = sdinv[s] * sdinv[d];
  }
}

// ---------------------------------------------------------------------------
// CSR build for the causal-attention mask C (batch-independent, ~9 nnz/row).
// ---------------------------------------------------------------------------
__global__ __launch_bounds__(512) void k_ccsr(const int* __restrict__ ei,
                                              const float* __restrict__ Cmat,
                                              int* __restrict__ rp,
                                              int* __restrict__ ci,
                                              float* __restrict__ cw)
{
  __shared__ unsigned bm[512 * 16];      // 512 rows x 512-bit
  __shared__ int cnt[512];
  __shared__ int sval[512];
  __shared__ int cur[512];
  const int t = threadIdx.x;
  const int* src = ei;
  const int* dst = ei + NE;
  for (int i = t; i < 512 * 16; i += 512) bm[i] = 0u;
  __syncthreads();
  bm[t * 16 + (t >> 5)] |= (1u << (t & 31));
  cnt[t] = 1;
  __syncthreads();
  for (int e = t; e < NE; e += 512) {
    int r = src[e], c = dst[e];
    if (Cmat[(size_t)r * NN + c] > 0.f) {
      unsigned bit = 1u << (c & 31);
      unsigned old = atomicOr(&bm[r * 16 + (c >> 5)], bit);
      if (!(old & bit)) atomicAdd(&cnt[r], 1);
    }
  }
  __syncthreads();
  const int myc = cnt[t];
  sval[t] = myc;
  __syncthreads();
  for (int off = 1; off < 512; off <<= 1) {
    int add = (t >= off) ? sval[t - off] : 0;
    __syncthreads();
    sval[t] += add;
    __syncthreads();
  }
  const int excl = sval[t] - myc;
  rp[t] = excl;
  if (t == 511) rp[512] = excl + myc;
  ci[excl] = t;
  cw[excl] = Cmat[(size_t)t * NN + t];
  cur[t] = excl + 1;
  bm[t * 16 + (t >> 5)] &= ~(1u << (t & 31));
  __syncthreads();
  for (int e = t; e < NE; e += 512) {
    int r = src[e], c = dst[e];
    if (Cmat[(size_t)r * NN + c] > 0.f) {
      unsigned bit = 1u << (c & 31);
      unsigned old = atomicAnd(&bm[r * 16 + (c >> 5)], ~bit);
      if (old & bit) {
        int p = atomicAdd(&cur[r], 1);
        ci[p] = c;
        cw[p] = Cmat[(size_t)r * NN + c];
      }
    }
  }
}

// ---------------------------------------------------------------------------
// Sparse GCN aggregation body (R14: 2-deep pipeline, validated).
// ---------------------------------------------------------------------------
__device__ __forceinline__ void gcn_body(
    int bid, const unsigned short* __restrict__ hW,
    const int* __restrict__ rp, const int* __restrict__ ci,
    const float* __restrict__ cw, const float* __restrict__ bias,
    unsigned short* __restrict__ out, int OS, int OC0)
{
  const int i5 = bid >> 3;
  const int ng = i5 & 31;                // node-group varies fastest on XCD
  const int b = (bid & 7) * 32 + (i5 >> 5);
  const int t = threadIdx.x;
  const int node = ng * 16 + (t >> 4);
  const int f0 = (t & 15) * 8;

  float bcol[8];
  #pragma unroll
  for (int k = 0; k < 8; k++) bcol[k] = bias[f0 + k];

  const unsigned short* base = hW + (size_t)b * 512 * 128;
  const int beg = rp[node], end = rp[node + 1];
  float acc[8] = {0.f, 0.f, 0.f, 0.f, 0.f, 0.f, 0.f, 0.f};
  int j = beg;
  float w = cw[j];
  int m = ci[j];
  short8v v = *(const short8v*)&base[(size_t)m * 128 + f0];
  for (; j < end; ) {
    const int jn = (j + 1 < end) ? j + 1 : j;
    const float w2 = cw[jn];
    const int m2 = ci[jn];
    short8v v2 = *(const short8v*)&base[(size_t)m2 * 128 + f0];
    #pragma unroll
    for (int k = 0; k < 8; k++) acc[k] += w * bf2f((unsigned short)v[k]);
    j++;
    w = w2; v = v2;
  }
  short8v o;
  #pragma unroll
  for (int k = 0; k < 8; k++) {
    float vv = fmaxf(acc[k] + bcol[k], 0.f);
    o[k] = (short)f2bf(vv);
  }
  *(short8v*)&out[((size_t)(b * 512 + node)) * OS + OC0 + f0] = o;
}

__global__ __launch_bounds__(256) void k_gcn(
    const unsigned short* __restrict__ hW,
    const int* __restrict__ rp, const int* __restrict__ ci,
    const float* __restrict__ cw, const float* __restrict__ bias,
    unsigned short* __restrict__ out, int OS, int OC0)
{
  gcn_body(blockIdx.x, hW, rp, ci, cw, bias, out, OS, OC0);
}

// ---------------------------------------------------------------------------
// Sparse masked attention body (R8-validated 2-deep pipeline).
// ---------------------------------------------------------------------------
__device__ __forceinline__ void sattn_body(
    int bid, const unsigned short* __restrict__ Qbf,
    const unsigned short* __restrict__ Kbf, const unsigned short* __restrict__ Vbf,
    const int* __restrict__ rp, const int* __restrict__ ci,
    const float* __restrict__ cw, unsigned short* __restrict__ Ocb)
{
  const int i5 = bid >> 3;
  const int ng = i5 & 31;
  const int b = (bid & 7) * 32 + (i5 >> 5);
  const int t = threadIdx.x;
  const int node = ng * 16 + (t >> 4);
  const int f0 = (t & 15) * 8;
  const float scale = 0.088388347648318447f;   // 1/sqrt(128)

  const size_t rowq = ((size_t)(b * 512 + node)) * 128 + f0;
  short8v qv = *(const short8v*)&Qbf[rowq];
  float qf[8];
  #pragma unroll
  for (int k = 0; k < 8; k++) qf[k] = bf2f((unsigned short)qv[k]);

  const unsigned short* Kb = Kbf + (size_t)b * 512 * 128;
  const unsigned short* Vb = Vbf + (size_t)b * 512 * 128;
  const int beg = rp[node], end = rp[node + 1];
  float acc[8] = {0.f, 0.f, 0.f, 0.f, 0.f, 0.f, 0.f, 0.f};
  float sw = 0.f;
  int j = beg;
  float w0 = cw[j];
  int m = ci[j];
  short8v kv = *(const short8v*)&Kb[(size_t)m * 128 + f0];
  short8v vv = *(const short8v*)&Vb[(size_t)m * 128 + f0];
  for (; j < end; ) {
    const int jn = (j + 1 < end) ? j + 1 : j;
    const float w02 = cw[jn];
    const int m2 = ci[jn];
    short8v kv2 = *(const short8v*)&Kb[(size_t)m2 * 128 + f0];
    short8v vv2 = *(const short8v*)&Vb[(size_t)m2 * 128 + f0];
    float part = 0.f;
    #pragma unroll
    for (int k = 0; k < 8; k++) part += qf[k] * bf2f((unsigned short)kv[k]);
    part += __shfl_xor(part, 1);
    part += __shfl_xor(part, 2);
    part += __shfl_xor(part, 4);
    part += __shfl_xor(part, 8);       // all 16 lanes of the node hold S
    float w = __expf(part * scale) * w0;
    sw += w;
    #pragma unroll
    for (int k = 0; k < 8; k++) acc[k] += w * bf2f((unsigned short)vv[k]);
    j++;
    w0 = w02; kv = kv2; vv = vv2;
  }
  float inv = 1.0f / sw;
  short8v o;
  #pragma unroll
  for (int k = 0; k < 8; k++) o[k] = (short)f2bf(acc[k] * inv);
  *(short8v*)&Ocb[((size_t)(b * 512 + node)) * 256 + f0] = o;
}

// ---------------------------------------------------------------------------
// Merged GCN-L1 aggregation + sparse attention (R10).
// ---------------------------------------------------------------------------
__global__ __launch_bounds__(256) void k_gs(
    const unsigned short* __restrict__ hW,
    const int* __restrict__ grp, const int* __restrict__ gci,
    const float* __restrict__ gcw, const float* __restrict__ gbias,
    const unsigned short* __restrict__ Qbf, const unsigned short* __restrict__ Kbf,
    const unsigned short* __restrict__ Vbf,
    const int* __restrict__ arp, const int* __restrict__ aci,
    const float* __restrict__ acw,
    unsigned short* __restrict__ Dout)
{
  if (blockIdx.x < 8192)
    gcn_body(blockIdx.x, hW, grp, gci, gcw, gbias, Dout, 256, 128);
  else
    sattn_body(blockIdx.x - 8192, Qbf, Kbf, Vbf, arp, aci, acw, Dout);
}

// ---------------------------------------------------------------------------
// Weight transpose+convert (R7-proven LDS tile transpose, 56 blocks).
// ---------------------------------------------------------------------------
__global__ __launch_bounds__(256) void k_wt(
    const float* s0, const float* s1, const float* s2, const float* s3,
    const float* s4, const float* s5, const float* s6,
    unsigned short* d0, unsigned short* d1, unsigned short* d2, unsigned short* d3,
    unsigned short* d4, unsigned short* d5, unsigned short* d6)
{
  const float* srcs[7] = {s0, s1, s2, s3, s4, s5, s6};
  unsigned short* dsts[7] = {d0, d1, d2, d3, d4, d5, d6};
  const int Ks[7] = {64, 128, 128, 128, 128, 128, 256};
  const int j = blockIdx.x >> 3;
  const int nc = blockIdx.x & 7;
  const float* s = srcs[j];
  unsigned short* d = dsts[j];
  const int K = Ks[j];
  const int STRW = K + 8;
  const int n0 = nc * 16;
  __shared__ short tile[16 * 264];       // max stride 256+8
  const int t = threadIdx.x;
  for (int i = t; i < K * 16; i += 256) {
    int k = i >> 4, nn = i & 15;
    tile[nn * STRW + k] = (short)f2bf(s[k * 128 + n0 + nn]);
  }
  __syncthreads();
  for (int i = t; i < K * 2; i += 256) {   // K*16/8 vector stores
    int nn = (i * 8) / K;
    int k  = (i * 8) % K;
    *(short8v*)&d[(size_t)(n0 + nn) * K + k] =
        *(const short8v*)&tile[nn * STRW + k];
  }
}

// ---------------------------------------------------------------------------
// Wave-independent bf16 GEMM, 512-thread blocks (R13-proven).
// ---------------------------------------------------------------------------
template<bool RELU>
__global__ __launch_bounds__(512) void k_wgemm(
    const unsigned short* __restrict__ Abf,
    const unsigned short* __restrict__ Wt,
    const float* __restrict__ bias,
    unsigned short* __restrict__ Out)
{
  constexpr int STR = 136;                  // 128 + 8 pad
  __shared__ short Ws[128 * STR];           // 34816 B
  __shared__ short rep[8 * 2048];           // 32768 B, 4KB per wave
  const int t = threadIdx.x;
  const int wave = t >> 6, lane = t & 63;
  const int l15 = lane & 15, quad = lane >> 4;
  short* rw = rep + wave * 2048;

  for (int i = t; i < 128 * 16; i += 512) {
    int n = i >> 4, seg = i & 15;
    *(short8v*)&Ws[n * STR + seg * 8] =
        *(const short8v*)&Wt[(size_t)n * 128 + seg * 8];
  }
  float bcol[8];
  #pragma unroll
  for (int nt = 0; nt < 8; nt++) bcol[nt] = bias ? bias[nt * 16 + l15] : 0.f;
  __syncthreads();                          // Ws visible — the ONLY barrier

  const int nwaves = gridDim.x * 8;
  int tile = blockIdx.x * 8 + wave;
  short8v af[4], afn[4];
  if (tile < MROWS / 16) {
    #pragma unroll
    for (int dc = 0; dc < 4; dc++)
      af[dc] = *(const short8v*)&Abf[((size_t)(tile * 16 + l15)) * 128 + dc * 32 + quad * 8];
  }
  while (tile < MROWS / 16) {
    const int ntile = tile + nwaves;
    if (ntile < MROWS / 16) {
      #pragma unroll
      for (int dc = 0; dc < 4; dc++)
        afn[dc] = *(const short8v*)&Abf[((size_t)(ntile * 16 + l15)) * 128 + dc * 32 + quad * 8];
    }
    float4v acc[8];
    #pragma unroll
    for (int nt = 0; nt < 8; nt++) acc[nt] = (float4v){0.f, 0.f, 0.f, 0.f};
    #pragma unroll
    for (int k32 = 0; k32 < 4; k32++) {
      #pragma unroll
      for (int nt = 0; nt < 8; nt++) {
        short8v wf = *(const short8v*)&Ws[(nt * 16 + l15) * STR + k32 * 32 + quad * 8];
        acc[nt] = __builtin_amdgcn_mfma_f32_16x16x32_bf16(af[k32], wf, acc[nt], 0, 0, 0);
      }
    }
    #pragma unroll
    for (int nt = 0; nt < 8; nt++)
      #pragma unroll
      for (int r = 0; r < 4; r++) {
        float v = acc[nt][r] + bcol[nt];
        if (RELU) v = fmaxf(v, 0.f);
        rw[(quad * 4 + r) * 128 + nt * 16 + l15] = (short)f2bf(v);
      }
    asm volatile("s_waitcnt lgkmcnt(0)" ::: "memory");
    __builtin_amdgcn_sched_barrier(0);
    #pragma unroll
    for (int p = 0; p < 4; p++) {
      int row16 = (lane >> 4) + p * 4, seg = lane & 15;
      short8v vv = *(const short8v*)&rw[row16 * 128 + seg * 8];
      *(short8v*)&Out[((size_t)(tile * 16 + row16)) * 128 + seg * 8] = vv;
    }
    tile = ntile;
    #pragma unroll
    for (int dc = 0; dc < 4; dc++) af[dc] = afn[dc];
  }
}

// ---------------------------------------------------------------------------
// bf16 MFMA GEMM (R7-proven).  Used ONLY for the final fused-LN GEMM
// (KD=256, OMODE2).  LDS repack keeps fp32 stores full-line (R14 lesson).
// ---------------------------------------------------------------------------
#define GNT 4
template<int KD, bool RELU, bool BATCHW, int OMODE, bool AF32>
__global__ __launch_bounds__(256) void k_bgemm(
    const void* __restrict__ Ap, const unsigned short* __restrict__ Wt,
    const float* __restrict__ bias, void* __restrict__ Out, int OS,
    const float* __restrict__ lng, const float* __restrict__ lnb)
{
  constexpr int KCH = (KD < 128) ? KD : 128;
  constexpr int STR = KCH + 8;
  constexpr bool WONCE = (KD <= 128);
  constexpr int ASH = (64 * STR > 8192) ? 64 * STR : 8192;   // shorts
  constexpr int TRIPS = KCH / 32;        // staging iterations per thread
  __shared__ short lds[ASH + 128 * STR];
  short* As = lds;
  short* Ws = lds + ASH;
  const unsigned short* Abf = (const unsigned short*)Ap;
  const float* Af = (const float*)Ap;
  const int t = threadIdx.x;
  const int wave = t >> 6, lane = t & 63;
  const int l15 = lane & 15, quad = lane >> 4;

  short8v ap[TRIPS];
  float4 fa[TRIPS], fb[TRIPS];

  auto LOADC = [&](int rb, int kc) {
    #pragma unroll
    for (int j = 0; j < TRIPS; j++) {
      int i = t + j * 256;
      int r = i / (KCH / 8), seg = i % (KCH / 8);
      if (AF32) {
        const float* sp = &Af[(size_t)(rb + r) * KD + kc + seg * 8];
        fa[j] = *(const float4*)sp;
        fb[j] = *(const float4*)(sp + 4);
      } else {
        int arow = BATCHW ? ((rb & 511) + r) : (rb + r);
        ap[j] = *(const short8v*)&Abf[(size_t)arow * KD + kc + seg * 8];
      }
    }
  };
  auto STOREC = [&]() {
    #pragma unroll
    for (int j = 0; j < TRIPS; j++) {
      int i = t + j * 256;
      int r = i / (KCH / 8), seg = i % (KCH / 8);
      if (AF32) {
        short8v pk;
        pk[0] = (short)f2bf(fa[j].x); pk[1] = (short)f2bf(fa[j].y);
        pk[2] = (short)f2bf(fa[j].z); pk[3] = (short)f2bf(fa[j].w);
        pk[4] = (short)f2bf(fb[j].x); pk[5] = (short)f2bf(fb[j].y);
        pk[6] = (short)f2bf(fb[j].z); pk[7] = (short)f2bf(fb[j].w);
        *(short8v*)&As[r * STR + seg * 8] = pk;
      } else {
        *(short8v*)&As[r * STR + seg * 8] = ap[j];
      }
    }
  };

  float bcol[8];
  #pragma unroll
  for (int nt = 0; nt < 8; nt++) bcol[nt] = bias ? bias[nt * 16 + l15] : 0.f;
  float gcol[8], bbcol[8];
  if (OMODE == 2) {
    #pragma unroll
    for (int nt = 0; nt < 8; nt++) { gcol[nt] = lng[nt * 16 + l15]; bbcol[nt] = lnb[nt * 16 + l15]; }
  }

  for (int g = blockIdx.x; g < (MROWS / 64) / GNT; g += gridDim.x) {
    if (WONCE) {
      const int b0 = (g * GNT * 64) >> 9;
      const unsigned short* Wb = BATCHW ? (Wt + (size_t)b0 * 128 * KD) : Wt;
      for (int i = t; i < 128 * (KCH / 8); i += 256) {
        int n = i / (KCH / 8), seg = i % (KCH / 8);
        *(short8v*)&Ws[n * STR + seg * 8] =
            *(const short8v*)&Wb[(size_t)n * KD + seg * 8];
      }
    }
    LOADC(g * GNT * 64, 0);                // prologue prefetch: tile 0 chunk 0
    for (int tt = 0; tt < GNT; tt++) {
      const int tile = g * GNT + tt;
      const int rowbase = tile * 64;
      const int b = rowbase >> 9;
      float4v acc[8];
      #pragma unroll
      for (int nt = 0; nt < 8; nt++) acc[nt] = (float4v){0.f, 0.f, 0.f, 0.f};

      for (int kc = 0; kc < KD; kc += KCH) {
        __syncthreads();                   // protect prior reads of As/Ws/rep
        STOREC();                          // prefetched regs -> LDS
        if (!WONCE) {
          const unsigned short* Wb = BATCHW ? (Wt + (size_t)b * 128 * KD) : Wt;
          for (int i = t; i < 128 * (KCH / 8); i += 256) {
            int n = i / (KCH / 8), seg = i % (KCH / 8);
            *(short8v*)&Ws[n * STR + seg * 8] =
                *(const short8v*)&Wb[(size_t)n * KD + kc + seg * 8];
          }
        }
        __syncthreads();
        {
          int nkc = kc + KCH, ntt = tt;
          if (nkc >= KD) { nkc = 0; ntt = tt + 1; }
          if (ntt < GNT) LOADC((g * GNT + ntt) * 64, nkc);
        }
        #pragma unroll
        for (int k32 = 0; k32 < KCH / 32; k32++) {
          short8v af = *(const short8v*)&As[(wave * 16 + l15) * STR + k32 * 32 + quad * 8];
          #pragma unroll
          for (int nt = 0; nt < 8; nt++) {
            short8v wf = *(const short8v*)&Ws[(nt * 16 + l15) * STR + k32 * 32 + quad * 8];
            acc[nt] = __builtin_amdgcn_mfma_f32_16x16x32_bf16(af, wf, acc[nt], 0, 0, 0);
          }
        }
      }

      __syncthreads();                         // all waves done reading As/Ws
      if (OMODE == 0) {
        short* rep = As + wave * 2048;
        #pragma unroll
        for (int nt = 0; nt < 8; nt++)
          #pragma unroll
          for (int r = 0; r < 4; r++) {
            float v = acc[nt][r] + bcol[nt];
            if (RELU) v = fmaxf(v, 0.f);
            rep[(quad * 4 + r) * 128 + nt * 16 + l15] = (short)f2bf(v);
          }
        __syncthreads();
        unsigned short* Ob = (unsigned short*)Out;
        #pragma unroll
        for (int p = 0; p < 4; p++) {
          int row16 = (lane >> 4) + p * 4, seg = lane & 15;
          short8v vv = *(const short8v*)&rep[row16 * 128 + seg * 8];
          *(short8v*)&Ob[(size_t)(rowbase + wave * 16 + row16) * OS + seg * 8] = vv;
        }
      } else if (OMODE == 1) {
        short* rep = As + wave * 2048;         // [c:128][node:16]
        #pragma unroll
        for (int nt = 0; nt < 8; nt++)
          #pragma unroll
          for (int r = 0; r < 4; r++) {
            float v = acc[nt][r] + bcol[nt];
            if (RELU) v = fmaxf(v, 0.f);
            rep[(nt * 16 + l15) * 16 + quad * 4 + r] = (short)f2bf(v);
          }
        __syncthreads();
        unsigned short* Ob = (unsigned short*)Out;
        int node0 = (rowbase & 511) + wave * 16;
        #pragma unroll
        for (int p = 0; p < 4; p++) {
          int idx = p * 64 + lane, c = idx >> 1, half = idx & 1;
          short8v vv = *(const short8v*)&rep[c * 16 + half * 8];
          *(short8v*)&Ob[((size_t)(b * 128 + c)) * 512 + node0 + half * 8] = vv;
        }
      } else {
        float* repw = (float*)lds + wave * 2048;   // Ws chunk data dead here
        float vv[8][4];
        float s[4] = {0, 0, 0, 0}, ss[4] = {0, 0, 0, 0};
        #pragma unroll
        for (int nt = 0; nt < 8; nt++)
          #pragma unroll
          for (int r = 0; r < 4; r++) {
            float v = acc[nt][r] + bcol[nt];
            vv[nt][r] = v;
            s[r] += v; ss[r] += v * v;
          }
        #pragma unroll
        for (int r = 0; r < 4; r++) {
          s[r] += __shfl_xor(s[r], 1);  s[r] += __shfl_xor(s[r], 2);
          s[r] += __shfl_xor(s[r], 4);  s[r] += __shfl_xor(s[r], 8);
          ss[r] += __shfl_xor(ss[r], 1); ss[r] += __shfl_xor(ss[r], 2);
          ss[r] += __shfl_xor(ss[r], 4); ss[r] += __shfl_xor(ss[r], 8);
        }
        #pragma unroll
        for (int r = 0; r < 4; r++) {
          float mu = s[r] * (1.0f / 128.0f);
          float var = ss[r] * (1.0f / 128.0f) - mu * mu;
          float inv = rsqrtf(var + 1e-5f);
          #pragma unroll
          for (int nt = 0; nt < 8; nt++)
            repw[(quad * 4 + r) * 128 + nt * 16 + l15] =
                (vv[nt][r] - mu) * inv * gcol[nt] + bbcol[nt];
        }
        __syncthreads();
        float* Of = (float*)Out;
        #pragma unroll
        for (int p = 0; p < 8; p++) {
          int row16 = (lane >> 5) + p * 2, seg = lane & 31;
          float4 o = *(const float4*)&repw[row16 * 128 + seg * 4];
          *(float4*)&Of[(size_t)(rowbase + wave * 16 + row16) * 128 + seg * 4] = o;
        }
      }
    }
  }
}

// ---------------------------------------------------------------------------
// R13: fused h + 4-way GEMM, 512-thread blocks (8 waves share one Ws).
// ---------------------------------------------------------------------------
__global__ __launch_bounds__(512) void k_hqkv4(
    const float* __restrict__ x,
    const unsigned short* __restrict__ Wint,   // 128 x 64 bf16 (n*64+k)
    const float* __restrict__ bin,
    const unsigned short* __restrict__ W0, const unsigned short* __restrict__ W1,
    const unsigned short* __restrict__ W2, const unsigned short* __restrict__ W3,
    const float* __restrict__ b1, const float* __restrict__ b2,
    const float* __restrict__ b3,
    unsigned short* __restrict__ O0, unsigned short* __restrict__ O1,
    unsigned short* __restrict__ O2, unsigned short* __restrict__ O3)
{
  constexpr int STR = 136;                  // Ws stride (128 + 8)
  constexpr int RSTR = 136;                 // rep stride
  __shared__ short Ws[128 * STR];           // 34816 B
  __shared__ short rep[8 * 2304];           // 36864 B
  const int t = threadIdx.x;
  const int wave = t >> 6, lane = t & 63;
  const int l15 = lane & 15, quad = lane >> 4;
  short* rw = rep + wave * 2304;

  const unsigned short* Wsrc[4] = {W0, W1, W2, W3};
  const float* Bsrc[4] = {nullptr, b1, b2, b3};
  unsigned short* Osrc[4] = {O0, O1, O2, O3};

  float bh[8];
  #pragma unroll
  for (int nt = 0; nt < 8; nt++) bh[nt] = bin[nt * 16 + l15];

  for (int g = blockIdx.x; g < MROWS / 256; g += gridDim.x) {
    // ---- phase 0: stage W_int (128x64) into Ws
    __syncthreads();                      // protect prior Ws reads (loop)
    for (int i = t; i < 128 * 8; i += 512) {
      int n = i >> 3, seg = i & 7;
      *(short8v*)&Ws[n * STR + seg * 8] =
          *(const short8v*)&Wint[(size_t)n * 64 + seg * 8];
    }
    __syncthreads();                      // Wint visible

    // ---- phase 1: h fragments for the 2 x 128-row tiles (wave-private)
    short8v af_all[2][4];
    #pragma unroll
    for (int tt = 0; tt < 2; tt++) {
      const int row0 = (g * 2 + tt) * 128 + wave * 16;   // this wave's 16 rows
      const float* xp = &x[(size_t)(row0 + l15) * 64 + quad * 16];
      float4 fx0 = *(const float4*)(xp);
      float4 fx1 = *(const float4*)(xp + 4);
      float4 fx2 = *(const float4*)(xp + 8);
      float4 fx3 = *(const float4*)(xp + 12);
      short8v px0, px1;
      px0[0] = (short)f2bf(fx0.x); px0[1] = (short)f2bf(fx0.y);
      px0[2] = (short)f2bf(fx0.z); px0[3] = (short)f2bf(fx0.w);
      px0[4] = (short)f2bf(fx1.x); px0[5] = (short)f2bf(fx1.y);
      px0[6] = (short)f2bf(fx1.z); px0[7] = (short)f2bf(fx1.w);
      px1[0] = (short)f2bf(fx2.x); px1[1] = (short)f2bf(fx2.y);
      px1[2] = (short)f2bf(fx2.z); px1[3] = (short)f2bf(fx2.w);
      px1[4] = (short)f2bf(fx3.x); px1[5] = (short)f2bf(fx3.y);
      px1[6] = (short)f2bf(fx3.z); px1[7] = (short)f2bf(fx3.w);
      *(short8v*)&rw[l15 * 72 + quad * 16]     = px0;   // x tile: 16 x 72
      *(short8v*)&rw[l15 * 72 + quad * 16 + 8] = px1;
      asm volatile("s_waitcnt lgkmcnt(0)" ::: "memory");
      __builtin_amdgcn_sched_barrier(0);

      float4v hacc[8];
      #pragma unroll
      for (int nt = 0; nt < 8; nt++) hacc[nt] = (float4v){0.f, 0.f, 0.f, 0.f};
      #pragma unroll
      for (int k32 = 0; k32 < 2; k32++) {
        short8v ax = *(const short8v*)&rw[l15 * 72 + k32 * 32 + quad * 8];
        #pragma unroll
        for (int nt = 0; nt < 8; nt++) {
          short8v wf = *(const short8v*)&Ws[(nt * 16 + l15) * STR + k32 * 32 + quad * 8];
          hacc[nt] = __builtin_amdgcn_mfma_f32_16x16x32_bf16(ax, wf, hacc[nt], 0, 0, 0);
        }
      }
      #pragma unroll
      for (int nt = 0; nt < 8; nt++)
        #pragma unroll
        for (int r = 0; r < 4; r++) {
          float v = fmaxf(hacc[nt][r] + bh[nt], 0.f);
          rw[(quad * 4 + r) * RSTR + nt * 16 + l15] = (short)f2bf(v);
        }
      asm volatile("s_waitcnt lgkmcnt(0)" ::: "memory");
      __builtin_amdgcn_sched_barrier(0);
      #pragma unroll
      for (int dc = 0; dc < 4; dc++)
        af_all[tt][dc] = *(const short8v*)&rw[l15 * RSTR + dc * 32 + quad * 8];
    }

    // ---- phase 2: four weight sets, MFMA from register A-fragments
    #pragma unroll
    for (int s = 0; s < 4; s++) {
      __syncthreads();                 // protect Ws reads (phase 1 / prior s)
      for (int i = t; i < 128 * 16; i += 512) {
        int n = i >> 4, seg = i & 15;
        *(short8v*)&Ws[n * STR + seg * 8] =
            *(const short8v*)&Wsrc[s][(size_t)n * 128 + seg * 8];
      }
      float bcol[8];
      #pragma unroll
      for (int nt = 0; nt < 8; nt++) bcol[nt] = Bsrc[s] ? Bsrc[s][nt * 16 + l15] : 0.f;
      __syncthreads();                 // Ws visible

      #pragma unroll
      for (int tt = 0; tt < 2; tt++) {
        const int rowbase = (g * 2 + tt) * 128;
        float4v acc[8];
        #pragma unroll
        for (int nt = 0; nt < 8; nt++) acc[nt] = (float4v){0.f, 0.f, 0.f, 0.f};
        #pragma unroll
        for (int k32 = 0; k32 < 4; k32++) {
          #pragma unroll
          for (int nt = 0; nt < 8; nt++) {
            short8v wf = *(const short8v*)&Ws[(nt * 16 + l15) * STR + k32 * 32 + quad * 8];
            acc[nt] = __builtin_amdgcn_mfma_f32_16x16x32_bf16(af_all[tt][k32], wf, acc[nt], 0, 0, 0);
          }
        }
        #pragma unroll
        for (int nt = 0; nt < 8; nt++)
          #pragma unroll
          for (int r = 0; r < 4; r++) {
            float v = acc[nt][r] + bcol[nt];
            rw[(quad * 4 + r) * RSTR + nt * 16 + l15] = (short)f2bf(v);
          }
        asm volatile("s_waitcnt lgkmcnt(0)" ::: "memory");
        __builtin_amdgcn_sched_barrier(0);
        unsigned short* Ob = Osrc[s];
        #pragma unroll
        for (int p = 0; p < 4; p++) {
          int row16 = (lane >> 4) + p * 4, seg = lane & 15;
          short8v vv = *(const short8v*)&rw[row16 * RSTR + seg * 8];
          *(short8v*)&Ob[(size_t)(rowbase + wave * 16 + row16) * 128 + seg * 8] = vv;
        }
      }
    }
  }
}

// ---------------------------------------------------------------------------
// ws layout: 5 x 33.5MB slots (A0,B0,C0,D0[2]) + AUX.
// V bf16 overlays d_out first half; K bf16 (E0) overlays d_out second half.
// ---------------------------------------------------------------------------
extern "C" void kernel_launch(void* const* d_in, const int* in_sizes, int n_in,
                              void* d_out, int out_size, void* d_ws, size_t ws_size,
                              hipStream_t stream)
{
  const float* x     = (const float*)d_in[0];
  const int*   ei    = (const int*)d_in[1];
  const float* adj   = (const float*)d_in[2];
  const float* dmask = (const float*)d_in[3];
  const float* clog  = (const float*)d_in[4];
  const float* W_in  = (const float*)d_in[5];
  const float* b_in  = (const float*)d_in[6];
  const float* Wq    = (const float*)d_in[7];
  const float* bq    = (const float*)d_in[8];
  const float* Wk    = (const float*)d_in[9];
  const float* bk    = (const float*)d_in[10];
  const float* Wv    = (const float*)d_in[11];
  const float* bv    = (const float*)d_in[12];
  const float* gcnW  = (const float*)d_in[13];
  const float* gcnB  = (const float*)d_in[14];
  const float* Wf    = (const float*)d_in[15];
  const float* bf    = (const float*)d_in[16];
  const float* lng   = (const float*)d_in[17];
  const float* lnb   = (const float*)d_in[18];

  float* outp = (float*)d_out;
  float* Cmat = outp + OUT0;

  char* W = (char*)d_ws;
  const size_t SLOT = (size_t)MROWS * 128 * 2;       // 33,554,432 B
  unsigned short* A0 = (unsigned short*)(W);
  unsigned short* B0 = (unsigned short*)(W + SLOT);
  unsigned short* C0 = (unsigned short*)(W + 2 * SLOT);
  unsigned short* D0 = (unsigned short*)(W + 3 * SLOT);   // 2*SLOT bytes
  char* AUX = W + 5 * SLOT;
  int*   csr_rp = (int*)AUX;                              // 513 ints
  int*   csr_ci = csr_rp + 640;                           // 4608 ints
  float* csr_cw = (float*)(csr_ci + 4608);                // 4608 floats
  int*   crp    = (int*)(AUX + 131072);                   // C-CSR @128KB
  int*   cci    = crp + 640;                              // up to 8192
  float* ccw    = (float*)(cci + 8192);
  unsigned short* WB    = (unsigned short*)(AUX + 512 * 512 * 4) + 512 * 512 * 2;
  unsigned short* W_int = WB;            // 128x64
  unsigned short* Wqt   = WB + 8192;     // 128x128
  unsigned short* Wkt   = Wqt + 16384;
  unsigned short* Wvt   = Wkt + 16384;
  unsigned short* G0t   = Wvt + 16384;
  unsigned short* G1t   = G0t + 16384;
  unsigned short* Wft   = G1t + 16384;   // 128x256

  unsigned short* Vbf = (unsigned short*)outp;       // d_out half 1 (scratch)
  unsigned short* E0  = Vbf + (size_t)MROWS * 128;   // d_out half 2 (scratch)

  // --- prep ---
  k_causalC<<<512, 256, 0, stream>>>(clog, adj, dmask, Cmat);
  k_csr<<<1, 512, 0, stream>>>(ei, csr_rp, csr_ci, csr_cw);
  k_ccsr<<<1, 512, 0, stream>>>(ei, Cmat, crp, cci, ccw);
  k_wt<<<56, 256, 0, stream>>>(W_in, Wq, Wk, Wv, gcnW, gcnW + HH * HH, Wf,
                               W_int, Wqt, Wkt, Wvt, G0t, G1t, Wft);

  // --- fused h + 4-way GEMM: hW0 -> A0, Q -> C0, K -> E0, V -> Vbf ---
  k_hqkv4<<<512, 512, 0, stream>>>(
      x, W_int, b_in, G0t, Wqt, Wkt, Wvt, bq, bk, bv, A0, C0, E0, Vbf);
  // --- GCN layer 0 aggregation: g1 = relu(gather(A0) + b0) -> B0 ---
  k_gcn<<<8192, 256, 0, stream>>>(A0, csr_rp, csr_ci, csr_cw, gcnB, B0, 128, 0);
  // --- GCN layer 1 GEMM (wave-independent, 512t): g1 @ W1 -> A0 ---
  k_wgemm<false><<<512, 512, 0, stream>>>(B0, G1t, nullptr, A0);
  // --- merged: GCN L1 aggregation -> D0 col128  ||  attention -> D0 col0 ---
  k_gs<<<16384, 256, 0, stream>>>(
      A0, csr_rp, csr_ci, csr_cw, gcnB + HH,
      C0, E0, Vbf, crp, cci, ccw, D0);
  // --- fuse + fused LayerNorm -> outp (proven k_bgemm OMODE2) ---
  k_bgemm<256, false, false, 2, false><<<512, 256, 0, stream>>>(
      D0, Wft, bf, outp, 128, lng, lnb);
}